// Round 16
// baseline (180.141 us; speedup 1.0000x reference)
//
#include <hip/hip_runtime.h>
#include <hip/hip_bf16.h>
#include <hip/hip_fp16.h>
#include <math.h>

constexpr int Bz = 4, Cc = 64, Hh = 128, Ww = 128, Kk = 9;
constexpr int HW = Hh * Ww;              // 16384
constexpr float EPSf = 1e-5f;
constexpr int CK = Cc * Kk;              // 576

typedef __attribute__((ext_vector_type(8))) short short8;
typedef __attribute__((ext_vector_type(4))) float f32x4;

__device__ __forceinline__ ushort f32_to_bf16(float f) {
    uint u = __float_as_uint(f);
    return (ushort)((u + 0x7fffu + ((u >> 16) & 1u)) >> 16);   // RNE
}
__device__ __forceinline__ float bf16_to_f32(ushort u) {
    return __uint_as_float((uint)u << 16);
}
__device__ __forceinline__ ushort f32_to_f16b(float f) {
    __half h = __float2half(f);
    return *reinterpret_cast<ushort*>(&h);
}
__device__ __forceinline__ __half2 u32_as_h2(uint u) {
    union { uint u; __half2 h; } c; c.u = u; return c.h;
}
__device__ __forceinline__ uint h2_as_u32(__half2 h) {
    union { uint u; __half2 h; } c; c.h = h; return c.u;
}

// ---- weight fragments (deform + offset-conv) in one launch, FP16 ----
__global__ void frag_kernel(const float* __restrict__ w1, const float* __restrict__ w2,
                            const float* __restrict__ ow1, const float* __restrict__ ow2,
                            ushort* __restrict__ wA1, ushort* __restrict__ wA2,
                            ushort* __restrict__ oA1, ushort* __restrict__ oA2) {
    int tid = blockIdx.x * 256 + threadIdx.x;     // 2*36864 + 2*18432 = 110592
    if (tid >= 110592) return;
    const float* src; ushort* dst; int e; int cout;
    if (tid < 36864)        { src = w1;  dst = wA1; e = tid;         cout = 64; }
    else if (tid < 73728)   { src = w2;  dst = wA2; e = tid - 36864; cout = 64; }
    else if (tid < 92160)   { src = ow1; dst = oA1; e = tid - 73728; cout = 18; }
    else                    { src = ow2; dst = oA2; e = tid - 92160; cout = 18; }
    int j = e & 7, l = (e >> 3) & 63, kk = (e >> 9) % 18, wo = e / 9216;
    int oc = wo * 16 + (l & 15);
    int kidx = kk * 32 + ((l >> 4) * 8) + j;
    int tap = kidx >> 6, c = kidx & 63;
    dst[e] = (oc < cout) ? f32_to_f16b(src[oc * CK + c * 9 + tap]) : (ushort)0;
}

// ---- NCHW fp32 -> NHWC fp16 (tiled transpose), for x only ----
__global__ __launch_bounds__(256)
void nhwc_kernel(const float* __restrict__ src, ushort* __restrict__ dst) {
    __shared__ float s_t[64][65];
    int blk = blockIdx.x;                 // Bz * (HW/64) = 1024
    int p0 = (blk & 255) * 64;
    int b = blk >> 8;
    int t = threadIdx.x;
    int tp = t & 63;
    #pragma unroll
    for (int i = 0; i < 16; i++) {
        int c = i * 4 + (t >> 6);
        s_t[c][tp] = src[((size_t)(b * 64 + c)) * HW + p0 + tp];
    }
    __syncthreads();
    #pragma unroll
    for (int i = 0; i < 16; i++) {
        int pl = i * 4 + (t >> 6);
        dst[((size_t)b * HW + p0 + pl) * 64 + tp] = f32_to_f16b(s_t[tp][pl]);
    }
}

// ---- fused offset-conv + deformable conv + GN partial reduce (FP16) ----
// block = 32 px of one (b,h) row, 512 threads.
// Wave-decoupled front: each wave redundantly computes the offset conv for
// its 16-px half (4x redundancy, MFMA pipe is ~5% busy), keeps offsets and
// coord records in wave-private LDS slices consumed by the SAME wave
// (lgkmcnt ordering, no __syncthreads). Barriers: 5 -> 2.
__global__ __launch_bounds__(512)
void deform_fused_kernel(const ushort* __restrict__ xnh, const ushort* __restrict__ wA,
                         const ushort* __restrict__ owA, const float* __restrict__ bias,
                         const float* __restrict__ obias, ushort* __restrict__ y,
                         float* __restrict__ part) {
    __shared__ __align__(16) ushort s_a[32 * 584];    // 37,376B: A[px][tap*64+c] f16
    __shared__ float s_offw[8][16 * 18];              // 9,216B: wave-private offsets
    __shared__ __align__(16) uint  s_awc[8][36][4];   // 4,608B: wave-private {yx,wy,wx}

    int blk = blockIdx.x;            // Bz*Hh*(Ww/32) = 2048
    int wt = blk & 3;
    int h  = (blk >> 2) & 127;
    int b  = blk >> 9;
    int w0 = wt * 32;
    int t = threadIdx.x;
    int wv = t >> 6, lane = t & 63;
    int g = lane >> 4, li = lane & 15;
    int ph = wv >> 2;                // which 16-px half this wave serves
    const ushort* xnb = xnh + (size_t)b * HW * 64;
    const char* xnc = reinterpret_cast<const char*>(xnb);

    // ---- phase A: FULL offset conv per wave for its 16-px half (f16 MFMA) ----
    {
        f32x4 oa0, oa1;
        #pragma unroll
        for (int r = 0; r < 4; r++) {
            oa0[r] = obias[g * 4 + r];
            oa1[r] = (g == 0 && r < 2) ? obias[16 + r] : 0.f;
        }
        const short8* owf = reinterpret_cast<const short8*>(owA) + lane;
        #pragma unroll
        for (int kk = 0; kk < 18; kk++) {
            int tap = kk >> 1;
            int ky = tap / 3 - 1, kx = tap - (tap / 3) * 3 - 1;
            int cb = (kk & 1) * 64 + g * 16;            // channel byte offset
            int gy = h + ky, gx = w0 + ph * 16 + li + kx;
            bool valid = ((unsigned)gy < 128u) && ((unsigned)gx < 128u);
            short8 bf = {0, 0, 0, 0, 0, 0, 0, 0};
            if (valid)
                bf = *reinterpret_cast<const short8*>(xnc + ((((gy << 7) + gx) << 7) + cb));
            oa0 = __builtin_amdgcn_mfma_f32_16x16x32_f16(owf[(0 * 18 + kk) * 64], bf, oa0, 0, 0, 0);
            oa1 = __builtin_amdgcn_mfma_f32_16x16x32_f16(owf[(1 * 18 + kk) * 64], bf, oa1, 0, 0, 0);
        }
        #pragma unroll
        for (int r = 0; r < 4; r++)
            s_offw[wv][li * 18 + g * 4 + r] = oa0[r];   // oc 0..15
        if (g == 0) {
            s_offw[wv][li * 18 + 16] = oa1[0];
            s_offw[wv][li * 18 + 17] = oa1[1];
        }
    }
    // wave-local: lgkmcnt ordering only, no barrier

    // ---- phase 0: this wave's 36 (px,tap) units -> compact coord records ----
    if (lane < 36) {
        int u = lane;
        int pxl = u / 9, k = u - pxl * 9;     // pxl 0..3
        int px = (wv << 2) + pxl;             // global px 0..31
        int phloc = px & 15;                  // row inside this wave's half
        int ky = k / 3 - 1, kx = k - (k / 3) * 3 - 1;
        float ody = s_offw[wv][phloc * 18 + 2 * k];
        float odx = s_offw[wv][phloc * 18 + 2 * k + 1];
        float cy = (float)(h + ky) + ody;
        float cx = (float)(w0 + px + kx) + odx;
        float fy = floorf(cy), fx = floorf(cx);
        int y0 = (int)fy, x0 = (int)fx;
        s_awc[wv][u][0] = (uint)(y0 & 0xffff) | ((uint)x0 << 16);
        s_awc[wv][u][1] = __float_as_uint(cy - fy);
        s_awc[wv][u][2] = __float_as_uint(cx - fx);
    }
    // wave-local again

    // ---- phase 1: gather (global, L2-resident) + packed f16 blend ----
    {
        int sub = lane >> 3;               // unit slot within iteration
        int ci  = lane & 7;                // channel group
        int co  = ci << 4;                 // byte offset of channel group
        char* s_ab = reinterpret_cast<char*>(s_a);
        #pragma unroll
        for (int i = 0; i < 5; i++) {
            int lu = i * 8 + sub;
            if (lu < 36) {
                int pxl = lu / 9, tap = lu - pxl * 9;
                int px = (wv << 2) + pxl;
                uint yx = s_awc[wv][lu][0];
                float wy = __uint_as_float(s_awc[wv][lu][1]);
                float wx = __uint_as_float(s_awc[wv][lu][2]);
                int y0 = (short)(yx & 0xffffu);
                int x0 = (short)(yx >> 16);
                int y1 = y0 + 1, x1 = x0 + 1;
                bool vy0 = (unsigned)y0 < 128u, vy1 = (unsigned)y1 < 128u;
                bool vx0 = (unsigned)x0 < 128u, vx1 = (unsigned)x1 < 128u;
                int yc0 = min(max(y0, 0), 127), yc1 = min(max(y1, 0), 127);
                int xc0 = min(max(x0, 0), 127), xc1 = min(max(x1, 0), 127);
                uint a00 = (uint)(((yc0 << 7) + xc0) << 7) + co;
                uint a01 = (uint)(((yc0 << 7) + xc1) << 7) + co;
                uint a10 = (uint)(((yc1 << 7) + xc0) << 7) + co;
                uint a11 = (uint)(((yc1 << 7) + xc1) << 7) + co;
                float w00 = (vy0 && vx0) ? (1.f - wy) * (1.f - wx) : 0.f;
                float w01 = (vy0 && vx1) ? (1.f - wy) * wx : 0.f;
                float w10 = (vy1 && vx0) ? wy * (1.f - wx) : 0.f;
                float w11 = (vy1 && vx1) ? wy * wx : 0.f;
                uint4 v00 = *reinterpret_cast<const uint4*>(xnc + a00);
                uint4 v01 = *reinterpret_cast<const uint4*>(xnc + a01);
                uint4 v10 = *reinterpret_cast<const uint4*>(xnc + a10);
                uint4 v11 = *reinterpret_cast<const uint4*>(xnc + a11);
                __half2 W00 = __float2half2_rn(w00);
                __half2 W01 = __float2half2_rn(w01);
                __half2 W10 = __float2half2_rn(w10);
                __half2 W11 = __float2half2_rn(w11);
                __half2 r0 = __hmul2(W00, u32_as_h2(v00.x));
                __half2 r1 = __hmul2(W00, u32_as_h2(v00.y));
                __half2 r2 = __hmul2(W00, u32_as_h2(v00.z));
                __half2 r3 = __hmul2(W00, u32_as_h2(v00.w));
                r0 = __hfma2(W01, u32_as_h2(v01.x), r0);
                r1 = __hfma2(W01, u32_as_h2(v01.y), r1);
                r2 = __hfma2(W01, u32_as_h2(v01.z), r2);
                r3 = __hfma2(W01, u32_as_h2(v01.w), r3);
                r0 = __hfma2(W10, u32_as_h2(v10.x), r0);
                r1 = __hfma2(W10, u32_as_h2(v10.y), r1);
                r2 = __hfma2(W10, u32_as_h2(v10.z), r2);
                r3 = __hfma2(W10, u32_as_h2(v10.w), r3);
                r0 = __hfma2(W11, u32_as_h2(v11.x), r0);
                r1 = __hfma2(W11, u32_as_h2(v11.y), r1);
                r2 = __hfma2(W11, u32_as_h2(v11.z), r2);
                r3 = __hfma2(W11, u32_as_h2(v11.w), r3);
                uint4 outv;
                outv.x = h2_as_u32(r0);
                outv.y = h2_as_u32(r1);
                outv.z = h2_as_u32(r2);
                outv.w = h2_as_u32(r3);
                *reinterpret_cast<uint4*>(s_ab + px * 1168 + tap * 128 + co) = outv;
            }
        }
    }
    __syncthreads();     // phase 2 reads s_a cross-wave

    // ---- phase 2: deform f16 MFMA. wave = (ph2, wo); D[oc][px]; bf16 store ----
    int wo = wv & 3, ph2 = wv >> 2;
    f32x4 acc;
    const float* bp = bias + wo * 16 + g * 4;
    acc.x = bp[0]; acc.y = bp[1]; acc.z = bp[2]; acc.w = bp[3];
    const short8* ap = reinterpret_cast<const short8*>(wA) + (wo * 18) * 64 + lane;
    const ushort* sp = s_a + (ph2 * 16 + li) * 584 + g * 8;
    #pragma unroll
    for (int kk = 0; kk < 18; kk++) {
        short8 af = ap[kk * 64];                                    // weights (arg0)
        short8 bf = *reinterpret_cast<const short8*>(sp + kk * 32); // samples (arg1)
        acc = __builtin_amdgcn_mfma_f32_16x16x32_f16(af, bf, acc, 0, 0, 0);
    }
    size_t ybase = ((size_t)(b * 64 + wo * 16 + g * 4)) * HW + h * Ww + w0 + ph2 * 16 + li;
    y[ybase]           = f32_to_bf16(acc.x);
    y[ybase + HW]      = f32_to_bf16(acc.y);
    y[ybase + 2 * HW]  = f32_to_bf16(acc.z);
    y[ybase + 3 * HW]  = f32_to_bf16(acc.w);

    // ---- epilogue: GN partial sums (from f32 accumulators) ----
    float s  = acc.x + acc.y + acc.z + acc.w;
    float s2 = acc.x * acc.x + acc.y * acc.y + acc.z * acc.z + acc.w * acc.w;
    #pragma unroll
    for (int o = 32; o > 0; o >>= 1) {
        s  += __shfl_down(s, o);
        s2 += __shfl_down(s2, o);
    }
    float* redbuf = reinterpret_cast<float*>(s_awc);   // s_awc is dead now
    if (lane == 0) { redbuf[wv * 2] = s; redbuf[wv * 2 + 1] = s2; }
    __syncthreads();
    if (t == 0) {
        float a = 0.f, c2 = 0.f;
        #pragma unroll
        for (int i = 0; i < 8; i++) { a += redbuf[i * 2]; c2 += redbuf[i * 2 + 1]; }
        part[blk * 2]     = a;
        part[blk * 2 + 1] = c2;
    }
}

// ---- GN stats: one block per sample, reduce 512 partial pairs once ----
__global__ void gn_stats_kernel(const float* __restrict__ part, float* __restrict__ stats) {
    __shared__ float ls[4][2];
    int b = blockIdx.x;
    int t = threadIdx.x;                          // 256
    int i0 = (b * 512 + t) * 2, i1 = (b * 512 + 256 + t) * 2;
    float s  = part[i0]     + part[i1];
    float s2 = part[i0 + 1] + part[i1 + 1];
    #pragma unroll
    for (int o = 32; o > 0; o >>= 1) {
        s  += __shfl_down(s, o);
        s2 += __shfl_down(s2, o);
    }
    int wave = t >> 6, lane = t & 63;
    if (lane == 0) { ls[wave][0] = s; ls[wave][1] = s2; }
    __syncthreads();
    if (t == 0) {
        float a = 0.f, c = 0.f;
        #pragma unroll
        for (int i = 0; i < 4; i++) { a += ls[i][0]; c += ls[i][1]; }
        const float n = (float)(Cc * HW);
        float m = a / n;
        float var = c / n - m * m;
        stats[b * 2]     = m;
        stats[b * 2 + 1] = rsqrtf(var + EPSf);
    }
}

// ---- block-1 finalize: normalize+ReLU+residual -> h1bf (bf16) + hnh (f16) ----
__global__ __launch_bounds__(256)
void gn_fin1_kernel(const ushort* __restrict__ y, const float* __restrict__ res,
                    const float* __restrict__ g, const float* __restrict__ be,
                    const float* __restrict__ stats, ushort* __restrict__ h1bf,
                    ushort* __restrict__ hnh) {
    __shared__ float s_t[64][65];
    int blk = blockIdx.x;                 // Bz * (HW/64) = 1024
    int p0 = (blk & 255) * 64;
    int b = blk >> 8;
    int t = threadIdx.x;
    int tp = t & 63;
    float m = stats[b * 2], rs = stats[b * 2 + 1];
    #pragma unroll
    for (int i = 0; i < 16; i++) {
        int c = i * 4 + (t >> 6);
        size_t idx = ((size_t)(b * 64 + c)) * HW + p0 + tp;
        float v = (bf16_to_f32(y[idx]) - m) * rs * g[c] + be[c];
        v = fmaxf(v, 0.f) + res[idx];
        h1bf[idx] = f32_to_bf16(v);
        s_t[c][tp] = v;
    }
    __syncthreads();
    #pragma unroll
    for (int i = 0; i < 16; i++) {
        int pl = i * 4 + (t >> 6);
        hnh[((size_t)b * HW + p0 + pl) * 64 + tp] = f32_to_f16b(s_t[tp][pl]);
    }
}

// ---- block-2 finalize: normalize + ReLU + residual(bf16) -> out (f32) ----
__global__ __launch_bounds__(256)
void gn_fin2_kernel(const ushort* __restrict__ y, const ushort* __restrict__ resbf,
                    const float* __restrict__ g, const float* __restrict__ be,
                    const float* __restrict__ stats, float* __restrict__ out) {
    int idx = (blockIdx.x * 256 + threadIdx.x) * 4;   // B*C*H*W / 4 threads
    int c = (idx >> 14) & 63;
    int b = idx >> 20;
    float m = stats[b * 2], rs = stats[b * 2 + 1];
    float gc = g[c], bc = be[c];
    ushort4 yv = *reinterpret_cast<const ushort4*>(y + idx);
    ushort4 rv = *reinterpret_cast<const ushort4*>(resbf + idx);
    float4 o;
    o.x = fmaxf((bf16_to_f32(yv.x) - m) * rs * gc + bc, 0.f) + bf16_to_f32(rv.x);
    o.y = fmaxf((bf16_to_f32(yv.y) - m) * rs * gc + bc, 0.f) + bf16_to_f32(rv.y);
    o.z = fmaxf((bf16_to_f32(yv.z) - m) * rs * gc + bc, 0.f) + bf16_to_f32(rv.z);
    o.w = fmaxf((bf16_to_f32(yv.w) - m) * rs * gc + bc, 0.f) + bf16_to_f32(rv.w);
    *reinterpret_cast<float4*>(out + idx) = o;
}

extern "C" void kernel_launch(void* const* d_in, const int* in_sizes, int n_in,
                              void* d_out, int out_size, void* d_ws, size_t ws_size,
                              hipStream_t stream) {
    const float* x   = (const float*)d_in[0];
    const float* w1  = (const float*)d_in[1];
    const float* b1  = (const float*)d_in[2];
    const float* ow1 = (const float*)d_in[3];
    const float* ob1 = (const float*)d_in[4];
    const float* g1  = (const float*)d_in[5];
    const float* be1 = (const float*)d_in[6];
    const float* w2  = (const float*)d_in[7];
    const float* b2  = (const float*)d_in[8];
    const float* ow2 = (const float*)d_in[9];
    const float* ob2 = (const float*)d_in[10];
    const float* g2  = (const float*)d_in[11];
    const float* be2 = (const float*)d_in[12];
    float* out = (float*)d_out;

    ushort* ybuf = (ushort*)d_ws;                        // 4,194,304 bf16 (8 MB)
    ushort* h1bf = ybuf + (size_t)Bz * Cc * HW;          // 4,194,304 bf16
    ushort* xnh  = h1bf + (size_t)Bz * Cc * HW;          // 4,194,304 f16 (NHWC)
    ushort* hnh  = xnh + (size_t)Bz * HW * 64;           // 4,194,304 f16 (NHWC)
    ushort* wA1  = hnh + (size_t)Bz * HW * 64;           // 36,864 f16
    ushort* wA2  = wA1 + 36864;                          // 36,864 f16
    ushort* owA1 = wA2 + 36864;                          // 18,432 f16
    ushort* owA2 = owA1 + 18432;                         // 18,432 f16
    float* part  = (float*)(owA2 + 18432);               // 4096 f
    float* stats = part + 4096;                          // 8 f

    frag_kernel<<<(110592 + 255) / 256, 256, 0, stream>>>(w1, w2, ow1, ow2, wA1, wA2, owA1, owA2);
    nhwc_kernel<<<Bz * (HW / 64), 256, 0, stream>>>(x, xnh);

    // block 1: offset-conv + deform_conv + GN-partial (fused) -> stats -> fin1
    deform_fused_kernel<<<Bz * Hh * (Ww / 32), 512, 0, stream>>>(xnh, wA1, owA1, b1, ob1, ybuf, part);
    gn_stats_kernel<<<Bz, 256, 0, stream>>>(part, stats);
    gn_fin1_kernel<<<Bz * (HW / 64), 256, 0, stream>>>(ybuf, x, g1, be1, stats, h1bf, hnh);

    // block 2: same, residual(bf16) from h1bf, finalize to out
    deform_fused_kernel<<<Bz * Hh * (Ww / 32), 512, 0, stream>>>(hnh, wA2, owA2, b2, ob2, ybuf, part);
    gn_stats_kernel<<<Bz, 256, 0, stream>>>(part, stats);
    gn_fin2_kernel<<<Bz * Cc * HW / 1024, 256, 0, stream>>>(ybuf, h1bf, g2, be2, stats, out);
}

// Round 17
// 100.394 us; speedup vs baseline: 1.7943x; 1.7943x over previous
//
#include <hip/hip_runtime.h>
#include <hip/hip_bf16.h>
#include <hip/hip_fp16.h>
#include <math.h>

constexpr int Bz = 4, Cc = 64, Hh = 128, Ww = 128, Kk = 9;
constexpr int HW = Hh * Ww;              // 16384
constexpr float EPSf = 1e-5f;
constexpr int CK = Cc * Kk;              // 576

// x-tile in LDS: 5 rows x 36 cols x 128B data, pitch 144B (bank spread)
constexpr int TROWS = 5, TCOLS = 36, TPITCH = 144;

typedef __attribute__((ext_vector_type(8))) short short8;
typedef __attribute__((ext_vector_type(4))) float f32x4;

__device__ __forceinline__ ushort f32_to_bf16(float f) {
    uint u = __float_as_uint(f);
    return (ushort)((u + 0x7fffu + ((u >> 16) & 1u)) >> 16);   // RNE
}
__device__ __forceinline__ float bf16_to_f32(ushort u) {
    return __uint_as_float((uint)u << 16);
}
__device__ __forceinline__ ushort f32_to_f16b(float f) {
    __half h = __float2half(f);
    return *reinterpret_cast<ushort*>(&h);
}
__device__ __forceinline__ __half2 u32_as_h2(uint u) {
    union { uint u; __half2 h; } c; c.u = u; return c.h;
}
__device__ __forceinline__ uint h2_as_u32(__half2 h) {
    union { uint u; __half2 h; } c; c.h = h; return c.u;
}

// ---- weight fragments (deform + offset-conv) in one launch, FP16 ----
__global__ void frag_kernel(const float* __restrict__ w1, const float* __restrict__ w2,
                            const float* __restrict__ ow1, const float* __restrict__ ow2,
                            ushort* __restrict__ wA1, ushort* __restrict__ wA2,
                            ushort* __restrict__ oA1, ushort* __restrict__ oA2) {
    int tid = blockIdx.x * 256 + threadIdx.x;     // 2*36864 + 2*18432 = 110592
    if (tid >= 110592) return;
    const float* src; ushort* dst; int e; int cout;
    if (tid < 36864)        { src = w1;  dst = wA1; e = tid;         cout = 64; }
    else if (tid < 73728)   { src = w2;  dst = wA2; e = tid - 36864; cout = 64; }
    else if (tid < 92160)   { src = ow1; dst = oA1; e = tid - 73728; cout = 18; }
    else                    { src = ow2; dst = oA2; e = tid - 92160; cout = 18; }
    int j = e & 7, l = (e >> 3) & 63, kk = (e >> 9) % 18, wo = e / 9216;
    int oc = wo * 16 + (l & 15);
    int kidx = kk * 32 + ((l >> 4) * 8) + j;
    int tap = kidx >> 6, c = kidx & 63;
    dst[e] = (oc < cout) ? f32_to_f16b(src[oc * CK + c * 9 + tap]) : (ushort)0;
}

// ---- NCHW fp32 -> NHWC fp16 (tiled transpose), for x only ----
__global__ __launch_bounds__(256)
void nhwc_kernel(const float* __restrict__ src, ushort* __restrict__ dst) {
    __shared__ float s_t[64][65];
    int blk = blockIdx.x;                 // Bz * (HW/64) = 1024
    int p0 = (blk & 255) * 64;
    int b = blk >> 8;
    int t = threadIdx.x;
    int tp = t & 63;
    #pragma unroll
    for (int i = 0; i < 16; i++) {
        int c = i * 4 + (t >> 6);
        s_t[c][tp] = src[((size_t)(b * 64 + c)) * HW + p0 + tp];
    }
    __syncthreads();
    #pragma unroll
    for (int i = 0; i < 16; i++) {
        int pl = i * 4 + (t >> 6);
        dst[((size_t)b * HW + p0 + pl) * 64 + tp] = f32_to_f16b(s_t[tp][pl]);
    }
}

// ---- fused offset-conv + deformable conv + GN partial reduce (FP16 path) ----
// block = 32 px of one (b,h) row, 512 threads; bf16 y output
__global__ __launch_bounds__(512)
void deform_fused_kernel(const ushort* __restrict__ xnh, const ushort* __restrict__ wA,
                         const ushort* __restrict__ owA, const float* __restrict__ bias,
                         const float* __restrict__ obias, ushort* __restrict__ y,
                         float* __restrict__ part) {
    __shared__ __align__(16) char   s_x[TROWS * TCOLS * TPITCH];   // 25,920 B (f16)
    __shared__ __align__(16) ushort s_a[32 * 584];    // A[px][tap*64+c] f16, +8 pad
    __shared__ __align__(16) uint   s_aw[32 * 9 * 8]; // per (px,tap): 4x{addr|flag,wgt}
    // off_s2 aliases s_a (phase A writes, phase 0 reads, phase 1 overwrites)
    float (*off_s2)[32][18] = reinterpret_cast<float (*)[32][18]>(s_a);

    int blk = blockIdx.x;            // Bz*Hh*(Ww/32) = 2048
    int wt = blk & 3;
    int h  = (blk >> 2) & 127;
    int b  = blk >> 9;
    int w0 = wt * 32;
    int t = threadIdx.x;
    int wv = t >> 6, lane = t & 63;
    const ushort* xnb = xnh + (size_t)b * HW * 64;
    const char* xnc = reinterpret_cast<const char*>(xnb);

    // ---- stage x-tile: rows h-2..h+2, cols w0-2..w0+33, zero-filled halo ----
    #pragma unroll
    for (int r = 0; r < 3; r++) {
        int e = r * 512 + t;                  // 1440 16B-chunks
        if (e < TROWS * TCOLS * 8) {
            int ch = e & 7, px = e >> 3;
            int row = px / TCOLS, col = px - row * TCOLS;
            int gy = h - 2 + row, gx = w0 - 2 + col;
            uint4 v = {0u, 0u, 0u, 0u};
            if ((unsigned)gy < 128u && (unsigned)gx < 128u)
                v = *reinterpret_cast<const uint4*>(xnc + ((((gy << 7) + gx) << 7) + ch * 16));
            *reinterpret_cast<uint4*>(&s_x[px * TPITCH + ch * 16]) = v;
        }
    }
    __syncthreads();

    // ---- phase A: offset conv via f16 MFMA from the LDS tile; 8 waves ----
    {
        int wo = wv & 1, ph = (wv >> 1) & 1, kh = wv >> 2;
        int g = lane >> 4, li = lane & 15;
        int px = ph * 16 + li;
        f32x4 oacc;
        #pragma unroll
        for (int r = 0; r < 4; r++) {
            int oc = wo * 16 + g * 4 + r;
            oacc[r] = (kh == 0 && oc < 18) ? obias[oc] : 0.f;
        }
        const short8* owp = reinterpret_cast<const short8*>(owA) + (wo * 18) * 64 + lane;
        #pragma unroll
        for (int kki = 0; kki < 9; kki++) {
            int kk = kh * 9 + kki;
            int tap = kk >> 1;
            int ky = tap / 3 - 1, kx = tap - (tap / 3) * 3 - 1;
            int cb = (kk & 1) * 64 + g * 16;
            short8 bf = *reinterpret_cast<const short8*>(
                &s_x[((ky + 2) * TCOLS + px + kx + 2) * TPITCH + cb]);
            short8 af = owp[kk * 64];
            oacc = __builtin_amdgcn_mfma_f32_16x16x32_f16(af, bf, oacc, 0, 0, 0);
        }
        #pragma unroll
        for (int r = 0; r < 4; r++) {
            int oc = wo * 16 + g * 4 + r;
            if (oc < 18) off_s2[kh][px][oc] = oacc[r];
        }
    }
    __syncthreads();

    // ---- phase 0: coords -> per-unit records {addr|flag, wgt} x4 ----
    uint aw_l[8];
    bool has_unit = (t < 288);
    if (has_unit) {
        int px = t / 9, k = t - px * 9;
        int ky = k / 3 - 1, kx = k - (k / 3) * 3 - 1;
        float ody = off_s2[0][px][2 * k]     + off_s2[1][px][2 * k];
        float odx = off_s2[0][px][2 * k + 1] + off_s2[1][px][2 * k + 1];
        float cy = (float)(h + ky) + ody;
        float cx = (float)(w0 + px + kx) + odx;
        float fy = floorf(cy), fx = floorf(cx);
        float wy = cy - fy, wx = cx - fx;
        int y0 = (int)fy, x0 = (int)fx;
        int y1 = y0 + 1, x1 = x0 + 1;
        bool vy0 = (unsigned)y0 < 128u, vy1 = (unsigned)y1 < 128u;
        bool vx0 = (unsigned)x0 < 128u, vx1 = (unsigned)x1 < 128u;
        int yc0 = min(max(y0, 0), 127), yc1 = min(max(y1, 0), 127);
        int xc0 = min(max(x0, 0), 127), xc1 = min(max(x1, 0), 127);
        int r0 = yc0 - (h - 2),  r1 = yc1 - (h - 2);
        int c0t = xc0 - (w0 - 2), c1t = xc1 - (w0 - 2);
        bool intile = ((unsigned)r0 < (unsigned)TROWS) && ((unsigned)r1 < (unsigned)TROWS)
                   && ((unsigned)c0t < (unsigned)TCOLS) && ((unsigned)c1t < (unsigned)TCOLS);
        uint a00, a01, a10, a11;
        if (intile) {
            a00 = (uint)((r0 * TCOLS + c0t) * TPITCH);
            a01 = (uint)((r0 * TCOLS + c1t) * TPITCH);
            a10 = (uint)((r1 * TCOLS + c0t) * TPITCH);
            a11 = (uint)((r1 * TCOLS + c1t) * TPITCH);
        } else {
            a00 = (uint)(((yc0 << 7) + xc0) << 7) | 0x80000000u;
            a01 = (uint)(((yc0 << 7) + xc1) << 7) | 0x80000000u;
            a10 = (uint)(((yc1 << 7) + xc0) << 7) | 0x80000000u;
            a11 = (uint)(((yc1 << 7) + xc1) << 7) | 0x80000000u;
        }
        aw_l[0] = a00; aw_l[1] = __float_as_uint((vy0 && vx0) ? (1.f - wy) * (1.f - wx) : 0.f);
        aw_l[2] = a01; aw_l[3] = __float_as_uint((vy0 && vx1) ? (1.f - wy) * wx : 0.f);
        aw_l[4] = a10; aw_l[5] = __float_as_uint((vy1 && vx0) ? wy * (1.f - wx) : 0.f);
        aw_l[6] = a11; aw_l[7] = __float_as_uint((vy1 && vx1) ? wy * wx : 0.f);
    }
    __syncthreads();                       // off_s2 (in s_a) now dead
    if (has_unit) {
        uint base = (uint)t * 8;
        #pragma unroll
        for (int i = 0; i < 8; i++) s_aw[base + i] = aw_l[i];
    }
    __syncthreads();

    // ---- phase 1: gather + PACKED f16 blend (v_pk_fma_f16, no unpack/pack) ----
    {
        int sub = lane >> 3;               // unit slot within iteration
        int ci  = lane & 7;                // channel group
        int co  = ci << 4;                 // byte offset of channel group
        char* s_ab = reinterpret_cast<char*>(s_a);
        #pragma unroll
        for (int i = 0; i < 5; i++) {
            int lu = i * 8 + sub;
            if (lu < 36) {
                int U = wv * 36 + lu;      // unit = px*9 + tap
                int px = U / 9;
                int tap = U - px * 9;
                uint4 q0 = *reinterpret_cast<const uint4*>(&s_aw[U * 8]);
                uint4 q1 = *reinterpret_cast<const uint4*>(&s_aw[U * 8 + 4]);
                uint4 v00, v01, v10, v11;
                if (!(q0.x & 0x80000000u)) {
                    v00 = *reinterpret_cast<const uint4*>(&s_x[q0.x + co]);
                    v01 = *reinterpret_cast<const uint4*>(&s_x[q0.z + co]);
                    v10 = *reinterpret_cast<const uint4*>(&s_x[q1.x + co]);
                    v11 = *reinterpret_cast<const uint4*>(&s_x[q1.z + co]);
                } else {
                    v00 = *reinterpret_cast<const uint4*>(xnc + ((q0.x & 0x7fffffffu) + co));
                    v01 = *reinterpret_cast<const uint4*>(xnc + ((q0.z & 0x7fffffffu) + co));
                    v10 = *reinterpret_cast<const uint4*>(xnc + ((q1.x & 0x7fffffffu) + co));
                    v11 = *reinterpret_cast<const uint4*>(xnc + ((q1.z & 0x7fffffffu) + co));
                }
                __half2 W00 = __float2half2_rn(__uint_as_float(q0.y));
                __half2 W01 = __float2half2_rn(__uint_as_float(q0.w));
                __half2 W10 = __float2half2_rn(__uint_as_float(q1.y));
                __half2 W11 = __float2half2_rn(__uint_as_float(q1.w));
                __half2 r0 = __hmul2(W00, u32_as_h2(v00.x));
                __half2 r1 = __hmul2(W00, u32_as_h2(v00.y));
                __half2 r2 = __hmul2(W00, u32_as_h2(v00.z));
                __half2 r3 = __hmul2(W00, u32_as_h2(v00.w));
                r0 = __hfma2(W01, u32_as_h2(v01.x), r0);
                r1 = __hfma2(W01, u32_as_h2(v01.y), r1);
                r2 = __hfma2(W01, u32_as_h2(v01.z), r2);
                r3 = __hfma2(W01, u32_as_h2(v01.w), r3);
                r0 = __hfma2(W10, u32_as_h2(v10.x), r0);
                r1 = __hfma2(W10, u32_as_h2(v10.y), r1);
                r2 = __hfma2(W10, u32_as_h2(v10.z), r2);
                r3 = __hfma2(W10, u32_as_h2(v10.w), r3);
                r0 = __hfma2(W11, u32_as_h2(v11.x), r0);
                r1 = __hfma2(W11, u32_as_h2(v11.y), r1);
                r2 = __hfma2(W11, u32_as_h2(v11.z), r2);
                r3 = __hfma2(W11, u32_as_h2(v11.w), r3);
                uint4 outv;
                outv.x = h2_as_u32(r0);
                outv.y = h2_as_u32(r1);
                outv.z = h2_as_u32(r2);
                outv.w = h2_as_u32(r3);
                *reinterpret_cast<uint4*>(s_ab + px * 1168 + tap * 128 + co) = outv;
            }
        }
    }
    __syncthreads();

    // ---- phase 2: deform f16 MFMA. wave = (ph, wo); D[oc][px]; bf16 store ----
    int wo = wv & 3, ph = wv >> 2;
    int g = lane >> 4, li = lane & 15;
    f32x4 acc;
    const float* bp = bias + wo * 16 + g * 4;
    acc.x = bp[0]; acc.y = bp[1]; acc.z = bp[2]; acc.w = bp[3];
    const short8* ap = reinterpret_cast<const short8*>(wA) + (wo * 18) * 64 + lane;
    const ushort* sp = s_a + (ph * 16 + li) * 584 + g * 8;
    #pragma unroll
    for (int kk = 0; kk < 18; kk++) {
        short8 af = ap[kk * 64];                                    // weights (arg0)
        short8 bf = *reinterpret_cast<const short8*>(sp + kk * 32); // samples (arg1)
        acc = __builtin_amdgcn_mfma_f32_16x16x32_f16(af, bf, acc, 0, 0, 0);
    }
    size_t ybase = ((size_t)(b * 64 + wo * 16 + g * 4)) * HW + h * Ww + w0 + ph * 16 + li;
    y[ybase]           = f32_to_bf16(acc.x);
    y[ybase + HW]      = f32_to_bf16(acc.y);
    y[ybase + 2 * HW]  = f32_to_bf16(acc.z);
    y[ybase + 3 * HW]  = f32_to_bf16(acc.w);

    // ---- epilogue: GN partial sums (from f32 accumulators) ----
    float s  = acc.x + acc.y + acc.z + acc.w;
    float s2 = acc.x * acc.x + acc.y * acc.y + acc.z * acc.z + acc.w * acc.w;
    #pragma unroll
    for (int o = 32; o > 0; o >>= 1) {
        s  += __shfl_down(s, o);
        s2 += __shfl_down(s2, o);
    }
    float* redbuf = reinterpret_cast<float*>(s_aw);   // s_aw is dead now
    if (lane == 0) { redbuf[wv * 2] = s; redbuf[wv * 2 + 1] = s2; }
    __syncthreads();
    if (t == 0) {
        float a = 0.f, c2 = 0.f;
        #pragma unroll
        for (int i = 0; i < 8; i++) { a += redbuf[i * 2]; c2 += redbuf[i * 2 + 1]; }
        part[blk * 2]     = a;
        part[blk * 2 + 1] = c2;
    }
}

// ---- GN stats: one block per sample, reduce 512 partial pairs once ----
__global__ void gn_stats_kernel(const float* __restrict__ part, float* __restrict__ stats) {
    __shared__ float ls[4][2];
    int b = blockIdx.x;
    int t = threadIdx.x;                          // 256
    int i0 = (b * 512 + t) * 2, i1 = (b * 512 + 256 + t) * 2;
    float s  = part[i0]     + part[i1];
    float s2 = part[i0 + 1] + part[i1 + 1];
    #pragma unroll
    for (int o = 32; o > 0; o >>= 1) {
        s  += __shfl_down(s, o);
        s2 += __shfl_down(s2, o);
    }
    int wave = t >> 6, lane = t & 63;
    if (lane == 0) { ls[wave][0] = s; ls[wave][1] = s2; }
    __syncthreads();
    if (t == 0) {
        float a = 0.f, c = 0.f;
        #pragma unroll
        for (int i = 0; i < 4; i++) { a += ls[i][0]; c += ls[i][1]; }
        const float n = (float)(Cc * HW);
        float m = a / n;
        float var = c / n - m * m;
        stats[b * 2]     = m;
        stats[b * 2 + 1] = rsqrtf(var + EPSf);
    }
}

// ---- block-1 finalize: normalize+ReLU+residual -> h1bf (bf16) + hnh (f16) ----
__global__ __launch_bounds__(256)
void gn_fin1_kernel(const ushort* __restrict__ y, const float* __restrict__ res,
                    const float* __restrict__ g, const float* __restrict__ be,
                    const float* __restrict__ stats, ushort* __restrict__ h1bf,
                    ushort* __restrict__ hnh) {
    __shared__ float s_t[64][65];
    int blk = blockIdx.x;                 // Bz * (HW/64) = 1024
    int p0 = (blk & 255) * 64;
    int b = blk >> 8;
    int t = threadIdx.x;
    int tp = t & 63;
    float m = stats[b * 2], rs = stats[b * 2 + 1];
    #pragma unroll
    for (int i = 0; i < 16; i++) {
        int c = i * 4 + (t >> 6);
        size_t idx = ((size_t)(b * 64 + c)) * HW + p0 + tp;
        float v = (bf16_to_f32(y[idx]) - m) * rs * g[c] + be[c];
        v = fmaxf(v, 0.f) + res[idx];
        h1bf[idx] = f32_to_bf16(v);
        s_t[c][tp] = v;
    }
    __syncthreads();
    #pragma unroll
    for (int i = 0; i < 16; i++) {
        int pl = i * 4 + (t >> 6);
        hnh[((size_t)b * HW + p0 + pl) * 64 + tp] = f32_to_f16b(s_t[tp][pl]);
    }
}

// ---- block-2 finalize: normalize + ReLU + residual(bf16) -> out (f32) ----
__global__ __launch_bounds__(256)
void gn_fin2_kernel(const ushort* __restrict__ y, const ushort* __restrict__ resbf,
                    const float* __restrict__ g, const float* __restrict__ be,
                    const float* __restrict__ stats, float* __restrict__ out) {
    int idx = (blockIdx.x * 256 + threadIdx.x) * 4;   // B*C*H*W / 4 threads
    int c = (idx >> 14) & 63;
    int b = idx >> 20;
    float m = stats[b * 2], rs = stats[b * 2 + 1];
    float gc = g[c], bc = be[c];
    ushort4 yv = *reinterpret_cast<const ushort4*>(y + idx);
    ushort4 rv = *reinterpret_cast<const ushort4*>(resbf + idx);
    float4 o;
    o.x = fmaxf((bf16_to_f32(yv.x) - m) * rs * gc + bc, 0.f) + bf16_to_f32(rv.x);
    o.y = fmaxf((bf16_to_f32(yv.y) - m) * rs * gc + bc, 0.f) + bf16_to_f32(rv.y);
    o.z = fmaxf((bf16_to_f32(yv.z) - m) * rs * gc + bc, 0.f) + bf16_to_f32(rv.z);
    o.w = fmaxf((bf16_to_f32(yv.w) - m) * rs * gc + bc, 0.f) + bf16_to_f32(rv.w);
    *reinterpret_cast<float4*>(out + idx) = o;
}

extern "C" void kernel_launch(void* const* d_in, const int* in_sizes, int n_in,
                              void* d_out, int out_size, void* d_ws, size_t ws_size,
                              hipStream_t stream) {
    const float* x   = (const float*)d_in[0];
    const float* w1  = (const float*)d_in[1];
    const float* b1  = (const float*)d_in[2];
    const float* ow1 = (const float*)d_in[3];
    const float* ob1 = (const float*)d_in[4];
    const float* g1  = (const float*)d_in[5];
    const float* be1 = (const float*)d_in[6];
    const float* w2  = (const float*)d_in[7];
    const float* b2  = (const float*)d_in[8];
    const float* ow2 = (const float*)d_in[9];
    const float* ob2 = (const float*)d_in[10];
    const float* g2  = (const float*)d_in[11];
    const float* be2 = (const float*)d_in[12];
    float* out = (float*)d_out;

    ushort* ybuf = (ushort*)d_ws;                        // 4,194,304 bf16 (8 MB)
    ushort* h1bf = ybuf + (size_t)Bz * Cc * HW;          // 4,194,304 bf16
    ushort* xnh  = h1bf + (size_t)Bz * Cc * HW;          // 4,194,304 f16 (NHWC)
    ushort* hnh  = xnh + (size_t)Bz * HW * 64;           // 4,194,304 f16 (NHWC)
    ushort* wA1  = hnh + (size_t)Bz * HW * 64;           // 36,864 f16
    ushort* wA2  = wA1 + 36864;                          // 36,864 f16
    ushort* owA1 = wA2 + 36864;                          // 18,432 f16
    ushort* owA2 = owA1 + 18432;                         // 18,432 f16
    float* part  = (float*)(owA2 + 18432);               // 4096 f
    float* stats = part + 4096;                          // 8 f

    frag_kernel<<<(110592 + 255) / 256, 256, 0, stream>>>(w1, w2, ow1, ow2, wA1, wA2, owA1, owA2);
    nhwc_kernel<<<Bz * (HW / 64), 256, 0, stream>>>(x, xnh);

    // block 1: offset-conv + deform_conv + GN-partial (fused) -> stats -> fin1
    deform_fused_kernel<<<Bz * Hh * (Ww / 32), 512, 0, stream>>>(xnh, wA1, owA1, b1, ob1, ybuf, part);
    gn_stats_kernel<<<Bz, 256, 0, stream>>>(part, stats);
    gn_fin1_kernel<<<Bz * (HW / 64), 256, 0, stream>>>(ybuf, x, g1, be1, stats, h1bf, hnh);

    // block 2: same, residual(bf16) from h1bf, finalize to out
    deform_fused_kernel<<<Bz * Hh * (Ww / 32), 512, 0, stream>>>(hnh, wA2, owA2, b2, ob2, ybuf, part);
    gn_stats_kernel<<<Bz, 256, 0, stream>>>(part, stats);
    gn_fin2_kernel<<<Bz * Cc * HW / 1024, 256, 0, stream>>>(ybuf, h1bf, g2, be2, stats, out);
}

// Round 18
// 99.409 us; speedup vs baseline: 1.8121x; 1.0099x over previous
//
#include <hip/hip_runtime.h>
#include <hip/hip_bf16.h>
#include <hip/hip_fp16.h>
#include <math.h>

constexpr int Bz = 4, Cc = 64, Hh = 128, Ww = 128, Kk = 9;
constexpr int HW = Hh * Ww;              // 16384
constexpr float EPSf = 1e-5f;
constexpr int CK = Cc * Kk;              // 576

// x-tile in LDS: 5 rows x 36 cols x 128B data, pitch 144B (bank spread)
constexpr int TROWS = 5, TCOLS = 36, TPITCH = 144;

typedef __attribute__((ext_vector_type(8))) short short8;
typedef __attribute__((ext_vector_type(4))) float f32x4;

__device__ __forceinline__ ushort f32_to_bf16(float f) {
    uint u = __float_as_uint(f);
    return (ushort)((u + 0x7fffu + ((u >> 16) & 1u)) >> 16);   // RNE
}
__device__ __forceinline__ float bf16_to_f32(ushort u) {
    return __uint_as_float((uint)u << 16);
}
__device__ __forceinline__ ushort f32_to_f16b(float f) {
    __half h = __float2half(f);
    return *reinterpret_cast<ushort*>(&h);
}
__device__ __forceinline__ __half2 u32_as_h2(uint u) {
    union { uint u; __half2 h; } c; c.u = u; return c.h;
}
__device__ __forceinline__ uint h2_as_u32(__half2 h) {
    union { uint u; __half2 h; } c; c.h = h; return c.u;
}

// ---- weight fragments (deform + offset-conv) in one launch, FP16 ----
__global__ void frag_kernel(const float* __restrict__ w1, const float* __restrict__ w2,
                            const float* __restrict__ ow1, const float* __restrict__ ow2,
                            ushort* __restrict__ wA1, ushort* __restrict__ wA2,
                            ushort* __restrict__ oA1, ushort* __restrict__ oA2) {
    int tid = blockIdx.x * 256 + threadIdx.x;     // 2*36864 + 2*18432 = 110592
    if (tid >= 110592) return;
    const float* src; ushort* dst; int e; int cout;
    if (tid < 36864)        { src = w1;  dst = wA1; e = tid;         cout = 64; }
    else if (tid < 73728)   { src = w2;  dst = wA2; e = tid - 36864; cout = 64; }
    else if (tid < 92160)   { src = ow1; dst = oA1; e = tid - 73728; cout = 18; }
    else                    { src = ow2; dst = oA2; e = tid - 92160; cout = 18; }
    int j = e & 7, l = (e >> 3) & 63, kk = (e >> 9) % 18, wo = e / 9216;
    int oc = wo * 16 + (l & 15);
    int kidx = kk * 32 + ((l >> 4) * 8) + j;
    int tap = kidx >> 6, c = kidx & 63;
    dst[e] = (oc < cout) ? f32_to_f16b(src[oc * CK + c * 9 + tap]) : (ushort)0;
}

// ---- NCHW fp32 -> NHWC fp16 (tiled transpose), for x only ----
__global__ __launch_bounds__(256)
void nhwc_kernel(const float* __restrict__ src, ushort* __restrict__ dst) {
    __shared__ float s_t[64][65];
    int blk = blockIdx.x;                 // Bz * (HW/64) = 1024
    int p0 = (blk & 255) * 64;
    int b = blk >> 8;
    int t = threadIdx.x;
    int tp = t & 63;
    #pragma unroll
    for (int i = 0; i < 16; i++) {
        int c = i * 4 + (t >> 6);
        s_t[c][tp] = src[((size_t)(b * 64 + c)) * HW + p0 + tp];
    }
    __syncthreads();
    #pragma unroll
    for (int i = 0; i < 16; i++) {
        int pl = i * 4 + (t >> 6);
        dst[((size_t)b * HW + p0 + pl) * 64 + tp] = f32_to_f16b(s_t[tp][pl]);
    }
}

// ---- fused offset-conv + deformable conv + GN partial reduce (FP16 path) ----
// block = 32 px of one (b,h) row, 512 threads; bf16 y output.
// vs r15: off_s2 is its OWN buffer (no s_a aliasing) -> one fewer barrier
// and no aw_l register round-trip in phase 0.
__global__ __launch_bounds__(512)
void deform_fused_kernel(const ushort* __restrict__ xnh, const ushort* __restrict__ wA,
                         const ushort* __restrict__ owA, const float* __restrict__ bias,
                         const float* __restrict__ obias, ushort* __restrict__ y,
                         float* __restrict__ part) {
    __shared__ __align__(16) char   s_x[TROWS * TCOLS * TPITCH];   // 25,920 B (f16)
    __shared__ __align__(16) ushort s_a[32 * 584];    // 37,376B: A[px][tap*64+c] f16
    __shared__ __align__(16) uint   s_aw[32 * 9 * 8]; // 9,216B: 4x{addr|flag,wgt}/unit
    __shared__ float off_s2[2][32][18];               // 4,608B: offsets (own buffer)

    int blk = blockIdx.x;            // Bz*Hh*(Ww/32) = 2048
    int wt = blk & 3;
    int h  = (blk >> 2) & 127;
    int b  = blk >> 9;
    int w0 = wt * 32;
    int t = threadIdx.x;
    int wv = t >> 6, lane = t & 63;
    const ushort* xnb = xnh + (size_t)b * HW * 64;
    const char* xnc = reinterpret_cast<const char*>(xnb);

    // ---- stage x-tile: rows h-2..h+2, cols w0-2..w0+33, zero-filled halo ----
    #pragma unroll
    for (int r = 0; r < 3; r++) {
        int e = r * 512 + t;                  // 1440 16B-chunks
        if (e < TROWS * TCOLS * 8) {
            int ch = e & 7, px = e >> 3;
            int row = px / TCOLS, col = px - row * TCOLS;
            int gy = h - 2 + row, gx = w0 - 2 + col;
            uint4 v = {0u, 0u, 0u, 0u};
            if ((unsigned)gy < 128u && (unsigned)gx < 128u)
                v = *reinterpret_cast<const uint4*>(xnc + ((((gy << 7) + gx) << 7) + ch * 16));
            *reinterpret_cast<uint4*>(&s_x[px * TPITCH + ch * 16]) = v;
        }
    }
    __syncthreads();

    // ---- phase A: offset conv via f16 MFMA from the LDS tile; 8 waves ----
    {
        int wo = wv & 1, ph = (wv >> 1) & 1, kh = wv >> 2;
        int g = lane >> 4, li = lane & 15;
        int px = ph * 16 + li;
        f32x4 oacc;
        #pragma unroll
        for (int r = 0; r < 4; r++) {
            int oc = wo * 16 + g * 4 + r;
            oacc[r] = (kh == 0 && oc < 18) ? obias[oc] : 0.f;
        }
        const short8* owp = reinterpret_cast<const short8*>(owA) + (wo * 18) * 64 + lane;
        #pragma unroll
        for (int kki = 0; kki < 9; kki++) {
            int kk = kh * 9 + kki;
            int tap = kk >> 1;
            int ky = tap / 3 - 1, kx = tap - (tap / 3) * 3 - 1;
            int cb = (kk & 1) * 64 + g * 16;
            short8 bf = *reinterpret_cast<const short8*>(
                &s_x[((ky + 2) * TCOLS + px + kx + 2) * TPITCH + cb]);
            short8 af = owp[kk * 64];
            oacc = __builtin_amdgcn_mfma_f32_16x16x32_f16(af, bf, oacc, 0, 0, 0);
        }
        #pragma unroll
        for (int r = 0; r < 4; r++) {
            int oc = wo * 16 + g * 4 + r;
            if (oc < 18) off_s2[kh][px][oc] = oacc[r];
        }
    }
    __syncthreads();

    // ---- phase 0: coords -> per-unit records, written DIRECTLY to s_aw ----
    if (t < 288) {
        int px = t / 9, k = t - px * 9;
        int ky = k / 3 - 1, kx = k - (k / 3) * 3 - 1;
        float ody = off_s2[0][px][2 * k]     + off_s2[1][px][2 * k];
        float odx = off_s2[0][px][2 * k + 1] + off_s2[1][px][2 * k + 1];
        float cy = (float)(h + ky) + ody;
        float cx = (float)(w0 + px + kx) + odx;
        float fy = floorf(cy), fx = floorf(cx);
        float wy = cy - fy, wx = cx - fx;
        int y0 = (int)fy, x0 = (int)fx;
        int y1 = y0 + 1, x1 = x0 + 1;
        bool vy0 = (unsigned)y0 < 128u, vy1 = (unsigned)y1 < 128u;
        bool vx0 = (unsigned)x0 < 128u, vx1 = (unsigned)x1 < 128u;
        int yc0 = min(max(y0, 0), 127), yc1 = min(max(y1, 0), 127);
        int xc0 = min(max(x0, 0), 127), xc1 = min(max(x1, 0), 127);
        int r0 = yc0 - (h - 2),  r1 = yc1 - (h - 2);
        int c0t = xc0 - (w0 - 2), c1t = xc1 - (w0 - 2);
        bool intile = ((unsigned)r0 < (unsigned)TROWS) && ((unsigned)r1 < (unsigned)TROWS)
                   && ((unsigned)c0t < (unsigned)TCOLS) && ((unsigned)c1t < (unsigned)TCOLS);
        uint a00, a01, a10, a11;
        if (intile) {
            a00 = (uint)((r0 * TCOLS + c0t) * TPITCH);
            a01 = (uint)((r0 * TCOLS + c1t) * TPITCH);
            a10 = (uint)((r1 * TCOLS + c0t) * TPITCH);
            a11 = (uint)((r1 * TCOLS + c1t) * TPITCH);
        } else {
            a00 = (uint)(((yc0 << 7) + xc0) << 7) | 0x80000000u;
            a01 = (uint)(((yc0 << 7) + xc1) << 7) | 0x80000000u;
            a10 = (uint)(((yc1 << 7) + xc0) << 7) | 0x80000000u;
            a11 = (uint)(((yc1 << 7) + xc1) << 7) | 0x80000000u;
        }
        uint base = (uint)t * 8;
        s_aw[base]     = a00; s_aw[base + 1] = __float_as_uint((vy0 && vx0) ? (1.f - wy) * (1.f - wx) : 0.f);
        s_aw[base + 2] = a01; s_aw[base + 3] = __float_as_uint((vy0 && vx1) ? (1.f - wy) * wx : 0.f);
        s_aw[base + 4] = a10; s_aw[base + 5] = __float_as_uint((vy1 && vx0) ? wy * (1.f - wx) : 0.f);
        s_aw[base + 6] = a11; s_aw[base + 7] = __float_as_uint((vy1 && vx1) ? wy * wx : 0.f);
    }
    __syncthreads();

    // ---- phase 1: gather + PACKED f16 blend (v_pk_fma_f16) ----
    {
        int sub = lane >> 3;               // unit slot within iteration
        int ci  = lane & 7;                // channel group
        int co  = ci << 4;                 // byte offset of channel group
        char* s_ab = reinterpret_cast<char*>(s_a);
        #pragma unroll
        for (int i = 0; i < 5; i++) {
            int lu = i * 8 + sub;
            if (lu < 36) {
                int U = wv * 36 + lu;      // unit = px*9 + tap
                int px = U / 9;
                int tap = U - px * 9;
                uint4 q0 = *reinterpret_cast<const uint4*>(&s_aw[U * 8]);
                uint4 q1 = *reinterpret_cast<const uint4*>(&s_aw[U * 8 + 4]);
                uint4 v00, v01, v10, v11;
                if (!(q0.x & 0x80000000u)) {
                    v00 = *reinterpret_cast<const uint4*>(&s_x[q0.x + co]);
                    v01 = *reinterpret_cast<const uint4*>(&s_x[q0.z + co]);
                    v10 = *reinterpret_cast<const uint4*>(&s_x[q1.x + co]);
                    v11 = *reinterpret_cast<const uint4*>(&s_x[q1.z + co]);
                } else {
                    v00 = *reinterpret_cast<const uint4*>(xnc + ((q0.x & 0x7fffffffu) + co));
                    v01 = *reinterpret_cast<const uint4*>(xnc + ((q0.z & 0x7fffffffu) + co));
                    v10 = *reinterpret_cast<const uint4*>(xnc + ((q1.x & 0x7fffffffu) + co));
                    v11 = *reinterpret_cast<const uint4*>(xnc + ((q1.z & 0x7fffffffu) + co));
                }
                __half2 W00 = __float2half2_rn(__uint_as_float(q0.y));
                __half2 W01 = __float2half2_rn(__uint_as_float(q0.w));
                __half2 W10 = __float2half2_rn(__uint_as_float(q1.y));
                __half2 W11 = __float2half2_rn(__uint_as_float(q1.w));
                __half2 r0 = __hmul2(W00, u32_as_h2(v00.x));
                __half2 r1 = __hmul2(W00, u32_as_h2(v00.y));
                __half2 r2 = __hmul2(W00, u32_as_h2(v00.z));
                __half2 r3 = __hmul2(W00, u32_as_h2(v00.w));
                r0 = __hfma2(W01, u32_as_h2(v01.x), r0);
                r1 = __hfma2(W01, u32_as_h2(v01.y), r1);
                r2 = __hfma2(W01, u32_as_h2(v01.z), r2);
                r3 = __hfma2(W01, u32_as_h2(v01.w), r3);
                r0 = __hfma2(W10, u32_as_h2(v10.x), r0);
                r1 = __hfma2(W10, u32_as_h2(v10.y), r1);
                r2 = __hfma2(W10, u32_as_h2(v10.z), r2);
                r3 = __hfma2(W10, u32_as_h2(v10.w), r3);
                r0 = __hfma2(W11, u32_as_h2(v11.x), r0);
                r1 = __hfma2(W11, u32_as_h2(v11.y), r1);
                r2 = __hfma2(W11, u32_as_h2(v11.z), r2);
                r3 = __hfma2(W11, u32_as_h2(v11.w), r3);
                uint4 outv;
                outv.x = h2_as_u32(r0);
                outv.y = h2_as_u32(r1);
                outv.z = h2_as_u32(r2);
                outv.w = h2_as_u32(r3);
                *reinterpret_cast<uint4*>(s_ab + px * 1168 + tap * 128 + co) = outv;
            }
        }
    }
    __syncthreads();

    // ---- phase 2: deform f16 MFMA. wave = (ph, wo); D[oc][px]; bf16 store ----
    int wo = wv & 3, ph = wv >> 2;
    int g = lane >> 4, li = lane & 15;
    f32x4 acc;
    const float* bp = bias + wo * 16 + g * 4;
    acc.x = bp[0]; acc.y = bp[1]; acc.z = bp[2]; acc.w = bp[3];
    const short8* ap = reinterpret_cast<const short8*>(wA) + (wo * 18) * 64 + lane;
    const ushort* sp = s_a + (ph * 16 + li) * 584 + g * 8;
    #pragma unroll
    for (int kk = 0; kk < 18; kk++) {
        short8 af = ap[kk * 64];                                    // weights (arg0)
        short8 bf = *reinterpret_cast<const short8*>(sp + kk * 32); // samples (arg1)
        acc = __builtin_amdgcn_mfma_f32_16x16x32_f16(af, bf, acc, 0, 0, 0);
    }
    size_t ybase = ((size_t)(b * 64 + wo * 16 + g * 4)) * HW + h * Ww + w0 + ph * 16 + li;
    y[ybase]           = f32_to_bf16(acc.x);
    y[ybase + HW]      = f32_to_bf16(acc.y);
    y[ybase + 2 * HW]  = f32_to_bf16(acc.z);
    y[ybase + 3 * HW]  = f32_to_bf16(acc.w);

    // ---- epilogue: GN partial sums (from f32 accumulators) ----
    float s  = acc.x + acc.y + acc.z + acc.w;
    float s2 = acc.x * acc.x + acc.y * acc.y + acc.z * acc.z + acc.w * acc.w;
    #pragma unroll
    for (int o = 32; o > 0; o >>= 1) {
        s  += __shfl_down(s, o);
        s2 += __shfl_down(s2, o);
    }
    float* redbuf = reinterpret_cast<float*>(s_aw);   // s_aw is dead now
    if (lane == 0) { redbuf[wv * 2] = s; redbuf[wv * 2 + 1] = s2; }
    __syncthreads();
    if (t == 0) {
        float a = 0.f, c2 = 0.f;
        #pragma unroll
        for (int i = 0; i < 8; i++) { a += redbuf[i * 2]; c2 += redbuf[i * 2 + 1]; }
        part[blk * 2]     = a;
        part[blk * 2 + 1] = c2;
    }
}

// ---- GN stats: one block per sample, reduce 512 partial pairs once ----
__global__ void gn_stats_kernel(const float* __restrict__ part, float* __restrict__ stats) {
    __shared__ float ls[4][2];
    int b = blockIdx.x;
    int t = threadIdx.x;                          // 256
    int i0 = (b * 512 + t) * 2, i1 = (b * 512 + 256 + t) * 2;
    float s  = part[i0]     + part[i1];
    float s2 = part[i0 + 1] + part[i1 + 1];
    #pragma unroll
    for (int o = 32; o > 0; o >>= 1) {
        s  += __shfl_down(s, o);
        s2 += __shfl_down(s2, o);
    }
    int wave = t >> 6, lane = t & 63;
    if (lane == 0) { ls[wave][0] = s; ls[wave][1] = s2; }
    __syncthreads();
    if (t == 0) {
        float a = 0.f, c = 0.f;
        #pragma unroll
        for (int i = 0; i < 4; i++) { a += ls[i][0]; c += ls[i][1]; }
        const float n = (float)(Cc * HW);
        float m = a / n;
        float var = c / n - m * m;
        stats[b * 2]     = m;
        stats[b * 2 + 1] = rsqrtf(var + EPSf);
    }
}

// ---- block-1 finalize: normalize+ReLU+residual -> h1bf (bf16) + hnh (f16) ----
__global__ __launch_bounds__(256)
void gn_fin1_kernel(const ushort* __restrict__ y, const float* __restrict__ res,
                    const float* __restrict__ g, const float* __restrict__ be,
                    const float* __restrict__ stats, ushort* __restrict__ h1bf,
                    ushort* __restrict__ hnh) {
    __shared__ float s_t[64][65];
    int blk = blockIdx.x;                 // Bz * (HW/64) = 1024
    int p0 = (blk & 255) * 64;
    int b = blk >> 8;
    int t = threadIdx.x;
    int tp = t & 63;
    float m = stats[b * 2], rs = stats[b * 2 + 1];
    #pragma unroll
    for (int i = 0; i < 16; i++) {
        int c = i * 4 + (t >> 6);
        size_t idx = ((size_t)(b * 64 + c)) * HW + p0 + tp;
        float v = (bf16_to_f32(y[idx]) - m) * rs * g[c] + be[c];
        v = fmaxf(v, 0.f) + res[idx];
        h1bf[idx] = f32_to_bf16(v);
        s_t[c][tp] = v;
    }
    __syncthreads();
    #pragma unroll
    for (int i = 0; i < 16; i++) {
        int pl = i * 4 + (t >> 6);
        hnh[((size_t)b * HW + p0 + pl) * 64 + tp] = f32_to_f16b(s_t[tp][pl]);
    }
}

// ---- block-2 finalize: normalize + ReLU + residual(bf16) -> out (f32) ----
__global__ __launch_bounds__(256)
void gn_fin2_kernel(const ushort* __restrict__ y, const ushort* __restrict__ resbf,
                    const float* __restrict__ g, const float* __restrict__ be,
                    const float* __restrict__ stats, float* __restrict__ out) {
    int idx = (blockIdx.x * 256 + threadIdx.x) * 4;   // B*C*H*W / 4 threads
    int c = (idx >> 14) & 63;
    int b = idx >> 20;
    float m = stats[b * 2], rs = stats[b * 2 + 1];
    float gc = g[c], bc = be[c];
    ushort4 yv = *reinterpret_cast<const ushort4*>(y + idx);
    ushort4 rv = *reinterpret_cast<const ushort4*>(resbf + idx);
    float4 o;
    o.x = fmaxf((bf16_to_f32(yv.x) - m) * rs * gc + bc, 0.f) + bf16_to_f32(rv.x);
    o.y = fmaxf((bf16_to_f32(yv.y) - m) * rs * gc + bc, 0.f) + bf16_to_f32(rv.y);
    o.z = fmaxf((bf16_to_f32(yv.z) - m) * rs * gc + bc, 0.f) + bf16_to_f32(rv.z);
    o.w = fmaxf((bf16_to_f32(yv.w) - m) * rs * gc + bc, 0.f) + bf16_to_f32(rv.w);
    *reinterpret_cast<float4*>(out + idx) = o;
}

extern "C" void kernel_launch(void* const* d_in, const int* in_sizes, int n_in,
                              void* d_out, int out_size, void* d_ws, size_t ws_size,
                              hipStream_t stream) {
    const float* x   = (const float*)d_in[0];
    const float* w1  = (const float*)d_in[1];
    const float* b1  = (const float*)d_in[2];
    const float* ow1 = (const float*)d_in[3];
    const float* ob1 = (const float*)d_in[4];
    const float* g1  = (const float*)d_in[5];
    const float* be1 = (const float*)d_in[6];
    const float* w2  = (const float*)d_in[7];
    const float* b2  = (const float*)d_in[8];
    const float* ow2 = (const float*)d_in[9];
    const float* ob2 = (const float*)d_in[10];
    const float* g2  = (const float*)d_in[11];
    const float* be2 = (const float*)d_in[12];
    float* out = (float*)d_out;

    ushort* ybuf = (ushort*)d_ws;                        // 4,194,304 bf16 (8 MB)
    ushort* h1bf = ybuf + (size_t)Bz * Cc * HW;          // 4,194,304 bf16
    ushort* xnh  = h1bf + (size_t)Bz * Cc * HW;          // 4,194,304 f16 (NHWC)
    ushort* hnh  = xnh + (size_t)Bz * HW * 64;           // 4,194,304 f16 (NHWC)
    ushort* wA1  = hnh + (size_t)Bz * HW * 64;           // 36,864 f16
    ushort* wA2  = wA1 + 36864;                          // 36,864 f16
    ushort* owA1 = wA2 + 36864;                          // 18,432 f16
    ushort* owA2 = owA1 + 18432;                         // 18,432 f16
    float* part  = (float*)(owA2 + 18432);               // 4096 f
    float* stats = part + 4096;                          // 8 f

    frag_kernel<<<(110592 + 255) / 256, 256, 0, stream>>>(w1, w2, ow1, ow2, wA1, wA2, owA1, owA2);
    nhwc_kernel<<<Bz * (HW / 64), 256, 0, stream>>>(x, xnh);

    // block 1: offset-conv + deform_conv + GN-partial (fused) -> stats -> fin1
    deform_fused_kernel<<<Bz * Hh * (Ww / 32), 512, 0, stream>>>(xnh, wA1, owA1, b1, ob1, ybuf, part);
    gn_stats_kernel<<<Bz, 256, 0, stream>>>(part, stats);
    gn_fin1_kernel<<<Bz * (HW / 64), 256, 0, stream>>>(ybuf, x, g1, be1, stats, h1bf, hnh);

    // block 2: same, residual(bf16) from h1bf, finalize to out
    deform_fused_kernel<<<Bz * Hh * (Ww / 32), 512, 0, stream>>>(hnh, wA2, owA2, b2, ob2, ybuf, part);
    gn_stats_kernel<<<Bz, 256, 0, stream>>>(part, stats);
    gn_fin2_kernel<<<Bz * Cc * HW / 1024, 256, 0, stream>>>(ybuf, h1bf, g2, be2, stats, out);
}